// Round 2
// baseline (115.896 us; speedup 1.0000x reference)
//
#include <hip/hip_runtime.h>
#include <math.h>

// GP_conv2D: N=8, IH=IW=32, IC=8, OC=16, 3x3 s1 p1, P=5, I_DIM=72
#define OC_N   16
#define I_DIM  72
#define PN     5
#define NEU    (OC_N * I_DIM)   // 1152
#define NF     32               // floats per neuron record (128 B)
#define RTOT   8192             // N * OH * OW
#define OUT_HALF (RTOT * OC_N)  // 131072

#if __has_builtin(__builtin_amdgcn_rcpf)
#define RCPF(x) __builtin_amdgcn_rcpf(x)
#else
#define RCPF(x) (1.0f / (x))
#endif
#if __has_builtin(__builtin_amdgcn_exp2f)
#define EXP2F(x) __builtin_amdgcn_exp2f(x)
#else
#define EXP2F(x) exp2f(x)
#endif

// Neuron record layout (32 floats):
// [0]=l2  [1]=pad  [2..6]=z[p]  [7..11]=alpha[p]
// [12..16]=Kinv diag  [17..26]=2*Kinv offdiag (01,02,03,04,12,13,14,23,24,34)
// [27..31]=pad

__global__ __launch_bounds__(64) void gp_prep_kernel(
    const float* __restrict__ zin, const float* __restrict__ hin,
    const float* __restrict__ rlin, float* __restrict__ nr) {
  int idx = blockIdx.x * blockDim.x + threadIdx.x;
  if (idx >= NEU) return;
  float x = rlin[idx];
  float sp = (x > 20.0f) ? x : log1pf(expf(x));   // softplus
  float l2 = sp * sp;
  float inv_l2 = 1.0f / l2;
  float zz[PN], hh[PN];
#pragma unroll
  for (int p = 0; p < PN; ++p) {
    zz[p] = zin[idx * PN + p];
    hh[p] = hin[idx * PN + p];
  }
  float A[PN][PN], B[PN][PN];
#pragma unroll
  for (int p = 0; p < PN; ++p) {
#pragma unroll
    for (int q = 0; q < PN; ++q) {
      float dz = zz[p] - zz[q];
      A[p][q] = expf(-0.5f * dz * dz * inv_l2);
      B[p][q] = (p == q) ? 1.0f : 0.0f;
    }
  }
#pragma unroll
  for (int p = 0; p < PN; ++p) A[p][p] += 1e-4f;  // jitter

  // Gauss-Jordan inverse (SPD + jitter -> no pivoting), fp32
#pragma unroll
  for (int c = 0; c < PN; ++c) {
    float pivinv = 1.0f / A[c][c];
#pragma unroll
    for (int j = 0; j < PN; ++j) { A[c][j] *= pivinv; B[c][j] *= pivinv; }
#pragma unroll
    for (int r = 0; r < PN; ++r) {
      if (r == c) continue;
      float f = A[r][c];
#pragma unroll
      for (int j = 0; j < PN; ++j) { A[r][j] -= f * A[c][j]; B[r][j] -= f * B[c][j]; }
    }
  }
  float alpha[PN];
#pragma unroll
  for (int p = 0; p < PN; ++p) {
    float s = 0.0f;
#pragma unroll
    for (int q = 0; q < PN; ++q) s += B[p][q] * hh[q];
    alpha[p] = s;
  }
  float* o = nr + idx * NF;
  o[0] = l2;
  o[1] = 0.0f;
#pragma unroll
  for (int p = 0; p < PN; ++p) {
    o[2 + p]  = zz[p];
    o[7 + p]  = alpha[p];
    o[12 + p] = B[p][p];
  }
  int j = 17;
#pragma unroll
  for (int p = 0; p < PN; ++p)
#pragma unroll
    for (int q = p + 1; q < PN; ++q) o[j++] = 2.0f * B[p][q];
  o[27] = o[28] = o[29] = o[30] = o[31] = 0.0f;
}

// Each block handles one tap-group (3 of 9 taps) for one output channel.
// Partial sums are atomically accumulated into ws buffers (3 writers/addr).
__global__ __launch_bounds__(256) void gp_main_kernel(
    const float* __restrict__ xm, const float* __restrict__ xv,
    const float* __restrict__ nr,
    float* __restrict__ mean_buf, float* __restrict__ qkq_buf) {
  const int o   = blockIdx.y;                     // wave-uniform channel
  const int seg = blockIdx.z;                     // tap-group = kh (0..2)
  const int r = blockIdx.x * 256 + threadIdx.x;   // im2col row, 0..8191
  const int n  = r >> 10;
  const int pix = r & 1023;
  const int oh = pix >> 5;
  const int ow = pix & 31;
  const float* nb = nr + o * (I_DIM * NF);

  float mean_acc = 0.0f;
  float qkq_acc  = 0.0f;

  const int ih = oh + seg - 1;                    // kh == seg
  const bool hvld = ((unsigned)ih < 32u);

#pragma unroll 1
  for (int kw = 0; kw < 3; ++kw) {
    const int k = seg * 3 + kw;                   // tap index in I ordering
    const int iw = ow + kw - 1;
    const bool vld = hvld & ((unsigned)iw < 32u);
    float mu[8], s2[8];
    if (vld) {
      const int base = ((n * 32 + ih) * 32 + iw) * 8;   // 32B-aligned
      const float4 a0 = *(const float4*)(xm + base);
      const float4 a1 = *(const float4*)(xm + base + 4);
      const float4 b0 = *(const float4*)(xv + base);
      const float4 b1 = *(const float4*)(xv + base + 4);
      mu[0]=a0.x; mu[1]=a0.y; mu[2]=a0.z; mu[3]=a0.w;
      mu[4]=a1.x; mu[5]=a1.y; mu[6]=a1.z; mu[7]=a1.w;
      s2[0]=b0.x; s2[1]=b0.y; s2[2]=b0.z; s2[3]=b0.w;
      s2[4]=b1.x; s2[5]=b1.y; s2[6]=b1.z; s2[7]=b1.w;
    } else {
#pragma unroll
      for (int c = 0; c < 8; ++c) { mu[c] = 0.0f; s2[c] = 0.0f; }
    }
#pragma unroll
    for (int c = 0; c < 8; ++c) {
      const float* p = nb + (c * 9 + k) * NF;   // uniform address -> s_load
      const float l2    = p[0];
      const float d     = l2 + s2[c];
      const float inv_d = RCPF(d);
      const float coef2 = l2 * inv_d;             // == l2/d == coef^2
      const float coef  = sqrtf(coef2);
      const float el    = -0.72134752044f * inv_d; // -0.5*log2(e)/d
      const float m     = mu[c];
      const float d0 = m - p[2];
      const float d1 = m - p[3];
      const float d2 = m - p[4];
      const float d3 = m - p[5];
      const float d4 = m - p[6];
      const float u0 = EXP2F(el * d0 * d0);
      const float u1 = EXP2F(el * d1 * d1);
      const float u2 = EXP2F(el * d2 * d2);
      const float u3 = EXP2F(el * d3 * d3);
      const float u4 = EXP2F(el * d4 * d4);
      const float dotA =
          fmaf(u0, p[7], fmaf(u1, p[8], fmaf(u2, p[9], fmaf(u3, p[10], u4 * p[11]))));
      const float t0 = fmaf(p[12], u0, fmaf(p[17], u1, fmaf(p[18], u2, fmaf(p[19], u3, p[20] * u4))));
      const float t1 = fmaf(p[13], u1, fmaf(p[21], u2, fmaf(p[22], u3, p[23] * u4)));
      const float t2 = fmaf(p[14], u2, fmaf(p[24], u3, p[25] * u4));
      const float t3 = fmaf(p[15], u3, p[26] * u4);
      const float t4 = p[16] * u4;
      const float quad =
          fmaf(u0, t0, fmaf(u1, t1, fmaf(u2, t2, fmaf(u3, t3, u4 * t4))));
      mean_acc = fmaf(coef, dotA, mean_acc);
      qkq_acc  = fmaf(coef2, quad, qkq_acc);
    }
  }
  const int oi = r * OC_N + o;
  atomicAdd(mean_buf + oi, mean_acc);
  atomicAdd(qkq_buf + oi, qkq_acc);
}

__global__ __launch_bounds__(256) void gp_final_kernel(
    const float* __restrict__ mean_buf, const float* __restrict__ qkq_buf,
    float* __restrict__ out) {
  const int i = blockIdx.x * 256 + threadIdx.x;
  out[i] = mean_buf[i];
  out[OUT_HALF + i] = fmaxf(72.0f - qkq_buf[i], 1e-6f);
}

extern "C" void kernel_launch(void* const* d_in, const int* in_sizes, int n_in,
                              void* d_out, int out_size, void* d_ws, size_t ws_size,
                              hipStream_t stream) {
  const float* xm = (const float*)d_in[0];   // x_mean [8,32,32,8]
  const float* xv = (const float*)d_in[1];   // x_var  [8,32,32,8]
  const float* z  = (const float*)d_in[2];   // [16,72,5]
  const float* h  = (const float*)d_in[3];   // [16,72,5]
  const float* rl = (const float*)d_in[4];   // [16,72]
  float* out = (float*)d_out;                // mean(131072) ++ var(131072)

  float* nr       = (float*)d_ws;                        // 147456 B
  float* mean_buf = (float*)((char*)d_ws + NEU * NF * 4);// 524288 B
  float* qkq_buf  = mean_buf + OUT_HALF;                 // 524288 B

  // zero the two accumulator buffers (contiguous, 1 MiB)
  hipMemsetAsync(mean_buf, 0, 2 * OUT_HALF * sizeof(float), stream);

  gp_prep_kernel<<<dim3((NEU + 63) / 64), dim3(64), 0, stream>>>(z, h, rl, nr);

  dim3 grid(RTOT / 256, OC_N, 3);            // (32, 16, 3) = 1536 wg
  gp_main_kernel<<<grid, dim3(256), 0, stream>>>(xm, xv, nr, mean_buf, qkq_buf);

  gp_final_kernel<<<dim3(OUT_HALF / 256), dim3(256), 0, stream>>>(mean_buf, qkq_buf, out);
}

// Round 3
// 91.279 us; speedup vs baseline: 1.2697x; 1.2697x over previous
//
#include <hip/hip_runtime.h>
#include <math.h>

// GP_conv2D: N=8, IH=IW=32, IC=8, OC=16, 3x3 s1 p1, P=5, I_DIM=72
#define OC_N   16
#define I_DIM  72
#define PN     5
#define NEU    (OC_N * I_DIM)   // 1152
#define NF     32               // floats per neuron record (128 B)
#define RTOT   8192             // N * OH * OW
#define OUT_HALF (RTOT * OC_N)  // 131072

#if __has_builtin(__builtin_amdgcn_rcpf)
#define RCPF(x) __builtin_amdgcn_rcpf(x)
#else
#define RCPF(x) (1.0f / (x))
#endif
#if __has_builtin(__builtin_amdgcn_exp2f)
#define EXP2F(x) __builtin_amdgcn_exp2f(x)
#else
#define EXP2F(x) exp2f(x)
#endif

// Neuron record layout (32 floats):
// [0]=l2  [1]=pad  [2..6]=z[p]  [7..11]=alpha[p]
// [12..16]=Kinv diag  [17..26]=2*Kinv offdiag (01,02,03,04,12,13,14,23,24,34)

__global__ __launch_bounds__(64) void gp_prep_kernel(
    const float* __restrict__ zin, const float* __restrict__ hin,
    const float* __restrict__ rlin, float* __restrict__ nr) {
  int idx = blockIdx.x * blockDim.x + threadIdx.x;
  if (idx >= NEU) return;
  float x = rlin[idx];
  float sp = (x > 20.0f) ? x : log1pf(expf(x));   // softplus
  float l2 = sp * sp;
  float inv_l2 = 1.0f / l2;
  float zz[PN], hh[PN];
#pragma unroll
  for (int p = 0; p < PN; ++p) {
    zz[p] = zin[idx * PN + p];
    hh[p] = hin[idx * PN + p];
  }
  float A[PN][PN], B[PN][PN];
#pragma unroll
  for (int p = 0; p < PN; ++p) {
#pragma unroll
    for (int q = 0; q < PN; ++q) {
      float dz = zz[p] - zz[q];
      A[p][q] = expf(-0.5f * dz * dz * inv_l2);
      B[p][q] = (p == q) ? 1.0f : 0.0f;
    }
  }
#pragma unroll
  for (int p = 0; p < PN; ++p) A[p][p] += 1e-4f;  // jitter

  // Gauss-Jordan inverse (SPD + jitter -> no pivoting), fp32
#pragma unroll
  for (int c = 0; c < PN; ++c) {
    float pivinv = 1.0f / A[c][c];
#pragma unroll
    for (int j = 0; j < PN; ++j) { A[c][j] *= pivinv; B[c][j] *= pivinv; }
#pragma unroll
    for (int r = 0; r < PN; ++r) {
      if (r == c) continue;
      float f = A[r][c];
#pragma unroll
      for (int j = 0; j < PN; ++j) { A[r][j] -= f * A[c][j]; B[r][j] -= f * B[c][j]; }
    }
  }
  float alpha[PN];
#pragma unroll
  for (int p = 0; p < PN; ++p) {
    float s = 0.0f;
#pragma unroll
    for (int q = 0; q < PN; ++q) s += B[p][q] * hh[q];
    alpha[p] = s;
  }
  float* o = nr + idx * NF;
  o[0] = l2;
  o[1] = 0.0f;
#pragma unroll
  for (int p = 0; p < PN; ++p) {
    o[2 + p]  = zz[p];
    o[7 + p]  = alpha[p];
    o[12 + p] = B[p][p];
  }
  int j = 17;
#pragma unroll
  for (int p = 0; p < PN; ++p)
#pragma unroll
    for (int q = p + 1; q < PN; ++q) o[j++] = 2.0f * B[p][q];
  o[27] = o[28] = o[29] = o[30] = o[31] = 0.0f;
}

// Block = (r-chunk, o, seg). seg covers taps [seg*TPS, seg*TPS+TPS).
// Partials stored with PLAIN coalesced stores (no atomics, no memset):
//   pm[(k_seg*16 + o)*8192 + r], pq likewise.
template <int TPS>
__global__ __launch_bounds__(256) void gp_main_kernel(
    const float* __restrict__ xm, const float* __restrict__ xv,
    const float* __restrict__ nr,
    float* __restrict__ pm, float* __restrict__ pq) {
  const int o   = blockIdx.y;                     // wave-uniform channel
  const int seg = blockIdx.z;
  const int r = blockIdx.x * 256 + threadIdx.x;   // im2col row, 0..8191
  const int n  = r >> 10;
  const int pix = r & 1023;
  const int oh = pix >> 5;
  const int ow = pix & 31;
  const float* nb = nr + o * (I_DIM * NF);

  float mean_acc = 0.0f;
  float qkq_acc  = 0.0f;

#pragma unroll
  for (int j = 0; j < TPS; ++j) {
    const int k  = seg * TPS + j;                 // tap index (uniform)
    const int kh = k / 3;
    const int kw = k - kh * 3;
    const int ih = oh + kh - 1;
    const int iw = ow + kw - 1;
    const bool vld = ((unsigned)ih < 32u) & ((unsigned)iw < 32u);
    float mu[8], s2[8];
    if (vld) {
      const int base = ((n * 32 + ih) * 32 + iw) * 8;   // 32B-aligned
      const float4 a0 = *(const float4*)(xm + base);
      const float4 a1 = *(const float4*)(xm + base + 4);
      const float4 b0 = *(const float4*)(xv + base);
      const float4 b1 = *(const float4*)(xv + base + 4);
      mu[0]=a0.x; mu[1]=a0.y; mu[2]=a0.z; mu[3]=a0.w;
      mu[4]=a1.x; mu[5]=a1.y; mu[6]=a1.z; mu[7]=a1.w;
      s2[0]=b0.x; s2[1]=b0.y; s2[2]=b0.z; s2[3]=b0.w;
      s2[4]=b1.x; s2[5]=b1.y; s2[6]=b1.z; s2[7]=b1.w;
    } else {
#pragma unroll
      for (int c = 0; c < 8; ++c) { mu[c] = 0.0f; s2[c] = 0.0f; }
    }
#pragma unroll
    for (int c = 0; c < 8; ++c) {
      const float* p = nb + (c * 9 + k) * NF;     // uniform address -> s_load
      const float l2    = p[0];
      const float d     = l2 + s2[c];
      const float inv_d = RCPF(d);
      const float coef2 = l2 * inv_d;             // == l2/d == coef^2
      const float coef  = sqrtf(coef2);
      const float el    = -0.72134752044f * inv_d; // -0.5*log2(e)/d
      const float m     = mu[c];
      const float d0 = m - p[2];
      const float d1 = m - p[3];
      const float d2 = m - p[4];
      const float d3 = m - p[5];
      const float d4 = m - p[6];
      const float u0 = EXP2F(el * d0 * d0);
      const float u1 = EXP2F(el * d1 * d1);
      const float u2 = EXP2F(el * d2 * d2);
      const float u3 = EXP2F(el * d3 * d3);
      const float u4 = EXP2F(el * d4 * d4);
      const float dotA =
          fmaf(u0, p[7], fmaf(u1, p[8], fmaf(u2, p[9], fmaf(u3, p[10], u4 * p[11]))));
      const float t0 = fmaf(p[12], u0, fmaf(p[17], u1, fmaf(p[18], u2, fmaf(p[19], u3, p[20] * u4))));
      const float t1 = fmaf(p[13], u1, fmaf(p[21], u2, fmaf(p[22], u3, p[23] * u4)));
      const float t2 = fmaf(p[14], u2, fmaf(p[24], u3, p[25] * u4));
      const float t3 = fmaf(p[15], u3, p[26] * u4);
      const float t4 = p[16] * u4;
      const float quad =
          fmaf(u0, t0, fmaf(u1, t1, fmaf(u2, t2, fmaf(u3, t3, u4 * t4))));
      mean_acc = fmaf(coef, dotA, mean_acc);
      qkq_acc  = fmaf(coef2, quad, qkq_acc);
    }
  }
  const int pi = (seg * OC_N + o) * RTOT + r;     // coalesced per wave
  pm[pi] = mean_acc;
  pq[pi] = qkq_acc;
}

template <int SEGS>
__global__ __launch_bounds__(256) void gp_final_kernel(
    const float* __restrict__ pm, const float* __restrict__ pq,
    float* __restrict__ out) {
  const int i = blockIdx.x * 256 + threadIdx.x;   // 0..131071
  const int r = i >> 4;
  const int o = i & 15;
  float m = 0.0f, q = 0.0f;
#pragma unroll
  for (int s = 0; s < SEGS; ++s) {
    const int pi = (s * OC_N + o) * RTOT + r;
    m += pm[pi];
    q += pq[pi];
  }
  out[i] = m;
  out[OUT_HALF + i] = fmaxf(72.0f - q, 1e-6f);
}

extern "C" void kernel_launch(void* const* d_in, const int* in_sizes, int n_in,
                              void* d_out, int out_size, void* d_ws, size_t ws_size,
                              hipStream_t stream) {
  const float* xm = (const float*)d_in[0];   // x_mean [8,32,32,8]
  const float* xv = (const float*)d_in[1];   // x_var  [8,32,32,8]
  const float* z  = (const float*)d_in[2];   // [16,72,5]
  const float* h  = (const float*)d_in[3];   // [16,72,5]
  const float* rl = (const float*)d_in[4];   // [16,72]
  float* out = (float*)d_out;                // mean(131072) ++ var(131072)

  float* nr = (float*)d_ws;                  // 147456 B
  float* pm = nr + NEU * NF;                 // SEGS*16*8192 floats
  const size_t need9 = (size_t)(NEU * NF + 2 * 9 * OC_N * RTOT) * 4;

  gp_prep_kernel<<<dim3((NEU + 63) / 64), dim3(64), 0, stream>>>(z, h, rl, nr);

  if (ws_size >= need9) {
    float* pq = pm + 9 * OC_N * RTOT;
    dim3 grid(RTOT / 256, OC_N, 9);          // 4608 wg -> 72 waves/CU nominal
    gp_main_kernel<1><<<grid, dim3(256), 0, stream>>>(xm, xv, nr, pm, pq);
    gp_final_kernel<9><<<dim3(OUT_HALF / 256), dim3(256), 0, stream>>>(pm, pq, out);
  } else {
    float* pq = pm + 3 * OC_N * RTOT;
    dim3 grid(RTOT / 256, OC_N, 3);          // 1536 wg
    gp_main_kernel<3><<<grid, dim3(256), 0, stream>>>(xm, xv, nr, pm, pq);
    gp_final_kernel<3><<<dim3(OUT_HALF / 256), dim3(256), 0, stream>>>(pm, pq, out);
  }
}

// Round 4
// 88.048 us; speedup vs baseline: 1.3163x; 1.0367x over previous
//
#include <hip/hip_runtime.h>
#include <math.h>

// GP_conv2D: N=8, IH=IW=32, IC=8, OC=16, 3x3 s1 p1, P=5, I_DIM=72
#define OC_N   16
#define I_DIM  72
#define PN     5
#define NEU    (OC_N * I_DIM)   // 1152
#define NF     32               // floats per neuron record (128 B)
#define RTOT   8192             // N * OH * OW
#define OUT_HALF (RTOT * OC_N)  // 131072
#define LOG2E  1.4426950408889634f
#define RLOG2E 0.6931471805599453f

#if __has_builtin(__builtin_amdgcn_rcpf)
#define RCPF(x) __builtin_amdgcn_rcpf(x)
#else
#define RCPF(x) (1.0f / (x))
#endif
#if __has_builtin(__builtin_amdgcn_exp2f)
#define EXP2F(x) __builtin_amdgcn_exp2f(x)
#else
#define EXP2F(x) exp2f(x)
#endif
#if __has_builtin(__builtin_amdgcn_logf)
#define LOG2F(x) __builtin_amdgcn_logf(x)
#else
#define LOG2F(x) log2f(x)
#endif

// Neuron record layout (32 floats):
// [0]=l2  [1]=pad  [2..6]=z[p]  [7..11]=alpha[p]
// [12..16]=Kinv diag  [17..26]=2*Kinv offdiag (01,02,03,04,12,13,14,23,24,34)

__global__ __launch_bounds__(256) void gp_prep_kernel(
    const float* __restrict__ zin, const float* __restrict__ hin,
    const float* __restrict__ rlin, float* __restrict__ nr) {
  int idx = blockIdx.x * blockDim.x + threadIdx.x;
  if (idx >= NEU) return;
  // softplus via native exp2/log2: log1p(e^x) = max(x,0) + ln(1 + e^-|x|)
  float x  = rlin[idx];
  float t  = EXP2F(-fabsf(x) * LOG2E);
  float sp = fmaxf(x, 0.0f) + LOG2F(1.0f + t) * RLOG2E;
  float l2 = sp * sp;
  float cexp = -0.5f * LOG2E * RCPF(l2);          // exponent scale for K

  float zz[PN], hh[PN];
#pragma unroll
  for (int p = 0; p < PN; ++p) {
    zz[p] = zin[idx * PN + p];
    hh[p] = hin[idx * PN + p];
  }
  float A[PN][PN], B[PN][PN];
#pragma unroll
  for (int p = 0; p < PN; ++p) {
#pragma unroll
    for (int q = 0; q < PN; ++q) {
      float dz = zz[p] - zz[q];
      A[p][q] = EXP2F(cexp * dz * dz);            // native v_exp_f32
      B[p][q] = (p == q) ? 1.0f : 0.0f;
    }
  }
#pragma unroll
  for (int p = 0; p < PN; ++p) A[p][p] += 1e-4f;  // jitter

  // Gauss-Jordan inverse (SPD + jitter -> no pivoting), fp32, native rcp
#pragma unroll
  for (int c = 0; c < PN; ++c) {
    float pivinv = RCPF(A[c][c]);
#pragma unroll
    for (int j = 0; j < PN; ++j) { A[c][j] *= pivinv; B[c][j] *= pivinv; }
#pragma unroll
    for (int r = 0; r < PN; ++r) {
      if (r == c) continue;
      float f = A[r][c];
#pragma unroll
      for (int j = 0; j < PN; ++j) { A[r][j] -= f * A[c][j]; B[r][j] -= f * B[c][j]; }
    }
  }
  float alpha[PN];
#pragma unroll
  for (int p = 0; p < PN; ++p) {
    float s = 0.0f;
#pragma unroll
    for (int q = 0; q < PN; ++q) s += B[p][q] * hh[q];
    alpha[p] = s;
  }
  float* o = nr + idx * NF;
  o[0] = l2;
  o[1] = 0.0f;
#pragma unroll
  for (int p = 0; p < PN; ++p) {
    o[2 + p]  = zz[p];
    o[7 + p]  = alpha[p];
    o[12 + p] = B[p][p];
  }
  int j = 17;
#pragma unroll
  for (int p = 0; p < PN; ++p)
#pragma unroll
    for (int q = p + 1; q < PN; ++q) o[j++] = 2.0f * B[p][q];
  o[27] = o[28] = o[29] = o[30] = o[31] = 0.0f;
}

// Block = (r-chunk, o, seg). seg covers taps [seg*TPS, seg*TPS+TPS).
// Partial (mean,qkq) stored as ONE coalesced float2 per (seg,o,r):
//   pmq[(seg*16 + o)*8192 + r]
template <int TPS>
__global__ __launch_bounds__(256) void gp_main_kernel(
    const float* __restrict__ xm, const float* __restrict__ xv,
    const float* __restrict__ nr, float2* __restrict__ pmq) {
  const int o   = blockIdx.y;                     // wave-uniform channel
  const int seg = blockIdx.z;
  const int r = blockIdx.x * 256 + threadIdx.x;   // im2col row, 0..8191
  const int n  = r >> 10;
  const int pix = r & 1023;
  const int oh = pix >> 5;
  const int ow = pix & 31;
  const float* nb = nr + o * (I_DIM * NF);

  float mean_acc = 0.0f;
  float qkq_acc  = 0.0f;

#pragma unroll
  for (int j = 0; j < TPS; ++j) {
    const int k  = seg * TPS + j;                 // tap index (uniform)
    const int kh = k / 3;
    const int kw = k - kh * 3;
    const int ih = oh + kh - 1;
    const int iw = ow + kw - 1;
    const bool vld = ((unsigned)ih < 32u) & ((unsigned)iw < 32u);
    float mu[8], s2[8];
    if (vld) {
      const int base = ((n * 32 + ih) * 32 + iw) * 8;   // 32B-aligned
      const float4 a0 = *(const float4*)(xm + base);
      const float4 a1 = *(const float4*)(xm + base + 4);
      const float4 b0 = *(const float4*)(xv + base);
      const float4 b1 = *(const float4*)(xv + base + 4);
      mu[0]=a0.x; mu[1]=a0.y; mu[2]=a0.z; mu[3]=a0.w;
      mu[4]=a1.x; mu[5]=a1.y; mu[6]=a1.z; mu[7]=a1.w;
      s2[0]=b0.x; s2[1]=b0.y; s2[2]=b0.z; s2[3]=b0.w;
      s2[4]=b1.x; s2[5]=b1.y; s2[6]=b1.z; s2[7]=b1.w;
    } else {
#pragma unroll
      for (int c = 0; c < 8; ++c) { mu[c] = 0.0f; s2[c] = 0.0f; }
    }
#pragma unroll
    for (int c = 0; c < 8; ++c) {
      const float* p = nb + (c * 9 + k) * NF;     // uniform address -> s_load
      const float l2    = p[0];
      const float d     = l2 + s2[c];
      const float inv_d = RCPF(d);
      const float coef2 = l2 * inv_d;             // == l2/d == coef^2
      const float coef  = sqrtf(coef2);
      const float el    = -0.72134752044f * inv_d; // -0.5*log2(e)/d
      const float m     = mu[c];
      const float d0 = m - p[2];
      const float d1 = m - p[3];
      const float d2 = m - p[4];
      const float d3 = m - p[5];
      const float d4 = m - p[6];
      const float u0 = EXP2F(el * d0 * d0);
      const float u1 = EXP2F(el * d1 * d1);
      const float u2 = EXP2F(el * d2 * d2);
      const float u3 = EXP2F(el * d3 * d3);
      const float u4 = EXP2F(el * d4 * d4);
      const float dotA =
          fmaf(u0, p[7], fmaf(u1, p[8], fmaf(u2, p[9], fmaf(u3, p[10], u4 * p[11]))));
      const float t0 = fmaf(p[12], u0, fmaf(p[17], u1, fmaf(p[18], u2, fmaf(p[19], u3, p[20] * u4))));
      const float t1 = fmaf(p[13], u1, fmaf(p[21], u2, fmaf(p[22], u3, p[23] * u4)));
      const float t2 = fmaf(p[14], u2, fmaf(p[24], u3, p[25] * u4));
      const float t3 = fmaf(p[15], u3, p[26] * u4);
      const float t4 = p[16] * u4;
      const float quad =
          fmaf(u0, t0, fmaf(u1, t1, fmaf(u2, t2, fmaf(u3, t3, u4 * t4))));
      mean_acc = fmaf(coef, dotA, mean_acc);
      qkq_acc  = fmaf(coef2, quad, qkq_acc);
    }
  }
  pmq[(seg * OC_N + o) * RTOT + r] = make_float2(mean_acc, qkq_acc);
}

// Thread j -> (o = j>>13, r = j&8191): the 2*SEGS partial reads are coalesced
// (r fastest); only the two 4B out-stores are strided (1 MB total, cheap).
template <int SEGS>
__global__ __launch_bounds__(256) void gp_final_kernel(
    const float2* __restrict__ pmq, float* __restrict__ out) {
  const int j = blockIdx.x * 256 + threadIdx.x;   // 0..131071
  const int o = j >> 13;
  const int r = j & 8191;
  float m = 0.0f, q = 0.0f;
#pragma unroll
  for (int s = 0; s < SEGS; ++s) {
    const float2 v = pmq[(s * OC_N + o) * RTOT + r];
    m += v.x;
    q += v.y;
  }
  const int i = r * OC_N + o;
  out[i] = m;
  out[OUT_HALF + i] = fmaxf(72.0f - q, 1e-6f);
}

extern "C" void kernel_launch(void* const* d_in, const int* in_sizes, int n_in,
                              void* d_out, int out_size, void* d_ws, size_t ws_size,
                              hipStream_t stream) {
  const float* xm = (const float*)d_in[0];   // x_mean [8,32,32,8]
  const float* xv = (const float*)d_in[1];   // x_var  [8,32,32,8]
  const float* z  = (const float*)d_in[2];   // [16,72,5]
  const float* h  = (const float*)d_in[3];   // [16,72,5]
  const float* rl = (const float*)d_in[4];   // [16,72]
  float* out = (float*)d_out;                // mean(131072) ++ var(131072)

  float* nr   = (float*)d_ws;                // 147456 B
  float2* pmq = (float2*)((char*)d_ws + NEU * NF * 4);
  const size_t need9 = (size_t)NEU * NF * 4 + (size_t)9 * OC_N * RTOT * 8;

  gp_prep_kernel<<<dim3((NEU + 255) / 256), dim3(256), 0, stream>>>(z, h, rl, nr);

  if (ws_size >= need9) {
    dim3 grid(RTOT / 256, OC_N, 9);          // 4608 wg -> ~8 waves/SIMD
    gp_main_kernel<1><<<grid, dim3(256), 0, stream>>>(xm, xv, nr, pmq);
    gp_final_kernel<9><<<dim3(OUT_HALF / 256), dim3(256), 0, stream>>>(pmq, out);
  } else {
    dim3 grid(RTOT / 256, OC_N, 3);          // 1536 wg
    gp_main_kernel<3><<<grid, dim3(256), 0, stream>>>(xm, xv, nr, pmq);
    gp_final_kernel<3><<<dim3(OUT_HALF / 256), dim3(256), 0, stream>>>(pmq, out);
  }
}

// Round 5
// 86.659 us; speedup vs baseline: 1.3374x; 1.0160x over previous
//
#include <hip/hip_runtime.h>
#include <math.h>

// GP_conv2D: N=8, IH=IW=32, IC=8, OC=16, 3x3 s1 p1, P=5, I_DIM=72
#define OC_N   16
#define I_DIM  72
#define PN     5
#define NEU    (OC_N * I_DIM)   // 1152
#define NF     32               // floats per neuron record (128 B)
#define RTOT   8192             // N * OH * OW
#define OUT_HALF (RTOT * OC_N)  // 131072
#define LOG2E  1.4426950408889634f
#define RLOG2E 0.6931471805599453f

#if __has_builtin(__builtin_amdgcn_rcpf)
#define RCPF(x) __builtin_amdgcn_rcpf(x)
#else
#define RCPF(x) (1.0f / (x))
#endif
#if __has_builtin(__builtin_amdgcn_exp2f)
#define EXP2F(x) __builtin_amdgcn_exp2f(x)
#else
#define EXP2F(x) exp2f(x)
#endif
#if __has_builtin(__builtin_amdgcn_logf)
#define LOG2F(x) __builtin_amdgcn_logf(x)
#else
#define LOG2F(x) log2f(x)
#endif

// Neuron record layout (32 floats):
// [0]=l2  [1]=pad  [2..6]=z[p]  [7..11]=alpha[p]
// [12..16]=Kinv diag  [17..26]=2*Kinv offdiag (01,02,03,04,12,13,14,23,24,34)

__global__ __launch_bounds__(256) void gp_prep_kernel(
    const float* __restrict__ zin, const float* __restrict__ hin,
    const float* __restrict__ rlin, float* __restrict__ nr) {
  int idx = blockIdx.x * blockDim.x + threadIdx.x;
  if (idx >= NEU) return;
  // softplus via native exp2/log2: log1p(e^x) = max(x,0) + ln(1 + e^-|x|)
  float x  = rlin[idx];
  float t  = EXP2F(-fabsf(x) * LOG2E);
  float sp = fmaxf(x, 0.0f) + LOG2F(1.0f + t) * RLOG2E;
  float l2 = sp * sp;
  float cexp = -0.5f * LOG2E * RCPF(l2);          // exponent scale for K

  float zz[PN], hh[PN];
#pragma unroll
  for (int p = 0; p < PN; ++p) {
    zz[p] = zin[idx * PN + p];
    hh[p] = hin[idx * PN + p];
  }
  float A[PN][PN], B[PN][PN];
#pragma unroll
  for (int p = 0; p < PN; ++p) {
#pragma unroll
    for (int q = 0; q < PN; ++q) {
      float dz = zz[p] - zz[q];
      A[p][q] = EXP2F(cexp * dz * dz);            // native v_exp_f32
      B[p][q] = (p == q) ? 1.0f : 0.0f;
    }
  }
#pragma unroll
  for (int p = 0; p < PN; ++p) A[p][p] += 1e-4f;  // jitter

  // Gauss-Jordan inverse (SPD + jitter -> no pivoting), fp32, native rcp
#pragma unroll
  for (int c = 0; c < PN; ++c) {
    float pivinv = RCPF(A[c][c]);
#pragma unroll
    for (int j = 0; j < PN; ++j) { A[c][j] *= pivinv; B[c][j] *= pivinv; }
#pragma unroll
    for (int r = 0; r < PN; ++r) {
      if (r == c) continue;
      float f = A[r][c];
#pragma unroll
      for (int j = 0; j < PN; ++j) { A[r][j] -= f * A[c][j]; B[r][j] -= f * B[c][j]; }
    }
  }
  float alpha[PN];
#pragma unroll
  for (int p = 0; p < PN; ++p) {
    float s = 0.0f;
#pragma unroll
    for (int q = 0; q < PN; ++q) s += B[p][q] * hh[q];
    alpha[p] = s;
  }
  float* o = nr + idx * NF;
  o[0] = l2;
  o[1] = 0.0f;
#pragma unroll
  for (int p = 0; p < PN; ++p) {
    o[2 + p]  = zz[p];
    o[7 + p]  = alpha[p];
    o[12 + p] = B[p][p];
  }
  int j = 17;
#pragma unroll
  for (int p = 0; p < PN; ++p)
#pragma unroll
    for (int q = p + 1; q < PN; ++q) o[j++] = 2.0f * B[p][q];
  o[27] = o[28] = o[29] = o[30] = o[31] = 0.0f;
}

// Fused main: block = (64 rows, 9 taps) = 576 threads (9 waves).
// Each wave owns one tap (ty is wave-uniform because blockDim.x == 64);
// per-row partials reduced through LDS; one store per row. No partial
// buffers, no final kernel.
__global__ __launch_bounds__(576) void gp_fused_kernel(
    const float* __restrict__ xm, const float* __restrict__ xv,
    const float* __restrict__ nr, float* __restrict__ out) {
  const int tx = threadIdx.x;                       // row-in-chunk 0..63
  const int k  = __builtin_amdgcn_readfirstlane(threadIdx.y);  // tap 0..8, scalar
  const int o  = blockIdx.y;                        // channel (uniform)
  const int r  = blockIdx.x * 64 + tx;              // im2col row
  const int n  = r >> 10;
  const int pix = r & 1023;
  const int oh = pix >> 5;
  const int ow = pix & 31;
  const float* nb = nr + o * (I_DIM * NF);

  const int kh = k / 3;
  const int kw = k - kh * 3;
  const int ih = oh + kh - 1;
  const int iw = ow + kw - 1;
  const bool vld = ((unsigned)ih < 32u) & ((unsigned)iw < 32u);

  float mu[8], s2[8];
  if (vld) {
    const int base = ((n * 32 + ih) * 32 + iw) * 8;   // 32B-aligned
    const float4 a0 = *(const float4*)(xm + base);
    const float4 a1 = *(const float4*)(xm + base + 4);
    const float4 b0 = *(const float4*)(xv + base);
    const float4 b1 = *(const float4*)(xv + base + 4);
    mu[0]=a0.x; mu[1]=a0.y; mu[2]=a0.z; mu[3]=a0.w;
    mu[4]=a1.x; mu[5]=a1.y; mu[6]=a1.z; mu[7]=a1.w;
    s2[0]=b0.x; s2[1]=b0.y; s2[2]=b0.z; s2[3]=b0.w;
    s2[4]=b1.x; s2[5]=b1.y; s2[6]=b1.z; s2[7]=b1.w;
  } else {
#pragma unroll
    for (int c = 0; c < 8; ++c) { mu[c] = 0.0f; s2[c] = 0.0f; }
  }

  float mean_acc = 0.0f;
  float qkq_acc  = 0.0f;
#pragma unroll
  for (int c = 0; c < 8; ++c) {
    const float* p = nb + (c * 9 + k) * NF;   // wave-uniform -> s_load
    const float l2    = p[0];
    const float d     = l2 + s2[c];
    const float inv_d = RCPF(d);
    const float coef2 = l2 * inv_d;             // == l2/d == coef^2
    const float coef  = sqrtf(coef2);
    const float el    = -0.72134752044f * inv_d; // -0.5*log2(e)/d
    const float m     = mu[c];
    const float d0 = m - p[2];
    const float d1 = m - p[3];
    const float d2 = m - p[4];
    const float d3 = m - p[5];
    const float d4 = m - p[6];
    const float u0 = EXP2F(el * d0 * d0);
    const float u1 = EXP2F(el * d1 * d1);
    const float u2 = EXP2F(el * d2 * d2);
    const float u3 = EXP2F(el * d3 * d3);
    const float u4 = EXP2F(el * d4 * d4);
    const float dotA =
        fmaf(u0, p[7], fmaf(u1, p[8], fmaf(u2, p[9], fmaf(u3, p[10], u4 * p[11]))));
    const float t0 = fmaf(p[12], u0, fmaf(p[17], u1, fmaf(p[18], u2, fmaf(p[19], u3, p[20] * u4))));
    const float t1 = fmaf(p[13], u1, fmaf(p[21], u2, fmaf(p[22], u3, p[23] * u4)));
    const float t2 = fmaf(p[14], u2, fmaf(p[24], u3, p[25] * u4));
    const float t3 = fmaf(p[15], u3, p[26] * u4);
    const float t4 = p[16] * u4;
    const float quad =
        fmaf(u0, t0, fmaf(u1, t1, fmaf(u2, t2, fmaf(u3, t3, u4 * t4))));
    mean_acc = fmaf(coef, dotA, mean_acc);
    qkq_acc  = fmaf(coef2, quad, qkq_acc);
  }

  __shared__ float2 red[9][64];
  red[threadIdx.y][tx] = make_float2(mean_acc, qkq_acc);
  __syncthreads();
  if (threadIdx.y == 0) {
    float m = mean_acc;
    float q = qkq_acc;
#pragma unroll
    for (int s = 1; s < 9; ++s) {
      const float2 v = red[s][tx];
      m += v.x;
      q += v.y;
    }
    const int i = r * OC_N + o;
    out[i] = m;
    out[OUT_HALF + i] = fmaxf(72.0f - q, 1e-6f);
  }
}

extern "C" void kernel_launch(void* const* d_in, const int* in_sizes, int n_in,
                              void* d_out, int out_size, void* d_ws, size_t ws_size,
                              hipStream_t stream) {
  const float* xm = (const float*)d_in[0];   // x_mean [8,32,32,8]
  const float* xv = (const float*)d_in[1];   // x_var  [8,32,32,8]
  const float* z  = (const float*)d_in[2];   // [16,72,5]
  const float* h  = (const float*)d_in[3];   // [16,72,5]
  const float* rl = (const float*)d_in[4];   // [16,72]
  float* out = (float*)d_out;                // mean(131072) ++ var(131072)
  float* nr  = (float*)d_ws;                 // 147456 B

  gp_prep_kernel<<<dim3((NEU + 255) / 256), dim3(256), 0, stream>>>(z, h, rl, nr);

  dim3 grid(RTOT / 64, OC_N);                // (128, 16) = 2048 blocks
  dim3 block(64, 9);                         // 576 threads = 9 waves
  gp_fused_kernel<<<grid, block, 0, stream>>>(xm, xv, nr, out);
}